// Round 16
// baseline (581.278 us; speedup 1.0000x reference)
//
#include <hip/hip_runtime.h>
#include <math.h>

#define TINYF 1.17549435e-38f
#define GMAX 16.0f   // hard upper bound on gumbel (15.9424) + slack
#define NT16 3125    // 50000 / 16 exactly
#define SPT16 49     // tiles per span (64 spans x 49 >= 3125)

typedef __attribute__((ext_vector_type(8))) short bf16x8;
typedef __attribute__((ext_vector_type(4))) float f32x4;

// ---------------- threefry2x32, key = (0, 42) ----------------
__device__ __forceinline__ unsigned rotl32(unsigned x, int r) {
  return (x << r) | (x >> (32 - r));
}

__device__ __forceinline__ unsigned tf2x32_xor(unsigned x0, unsigned x1) {
  const unsigned k0 = 0u, k1 = 42u, k2 = 0x1BD11BF0u;  // 0x1BD11BDA ^ 0 ^ 42
  x0 += k0; x1 += k1;
#define TFR(r) { x0 += x1; x1 = rotl32(x1, r); x1 ^= x0; }
  TFR(13) TFR(15) TFR(26) TFR(6)
  x0 += k1; x1 += k2 + 1u;
  TFR(17) TFR(29) TFR(16) TFR(24)
  x0 += k2; x1 += k0 + 2u;
  TFR(13) TFR(15) TFR(26) TFR(6)
  x0 += k0; x1 += k1 + 3u;
  TFR(17) TFR(29) TFR(16) TFR(24)
  x0 += k1; x1 += k2 + 4u;
  TFR(13) TFR(15) TFR(26) TFR(6)
  x0 += k2; x1 += k0 + 5u;
#undef TFR
  return x0 ^ x1;
}

// order-preserving float->uint (monotone)
__device__ __forceinline__ unsigned ordf(float v) {
  unsigned b = __float_as_uint(v);
  return (b & 0x80000000u) ? ~b : (b | 0x80000000u);
}
__device__ __forceinline__ float unordf(unsigned u) {
  unsigned b = (u & 0x80000000u) ? (u & 0x7FFFFFFFu) : ~u;
  return __uint_as_float(b);
}

// fp32 -> bf16 RNE (bit trick)
__device__ __forceinline__ unsigned short f2bf(float f) {
  unsigned u = __float_as_uint(f);
  unsigned r = u + 0x7FFFu + ((u >> 16) & 1u);
  return (unsigned short)(r >> 16);
}
__device__ __forceinline__ unsigned pk2(float a, float b) {
  return (unsigned)f2bf(a) | ((unsigned)f2bf(b) << 16);
}
// XOR swizzle within a 16-row x 256B tile (kills stride-256B bank conflicts)
__device__ __forceinline__ int bswz(int b) { return b ^ (((b >> 8) & 7) << 4); }

// ---- candidate resolution. Tier-2 threshold purely from rowslot (fresh,
// monotone; -3.4e38 before the first write -> self-seeding warmup: iter-0
// candidates all resolve, which replaces the old k_seed kernel). Fast
// u-space pre-test with HW exp (no false reject; ~2e-5 over-accept filtered
// by the exact path; d=-inf -> thr_u=0 -> pass-through, no NaN). ONE
// noinline copy, called only from dense per-wave drains.
__device__ __attribute__((noinline)) void resolve_cand(
    int R, int J, float s, float ERRC,
    const float* __restrict__ hfin, const float* __restrict__ items,
    unsigned long long* __restrict__ rowslot, const volatile unsigned* hiw) {
  const unsigned hi0 = hiw[2 * R + 1];
  const float tv = hi0 ? unordf(hi0) : -3.4e38f;
  const float thr2 = tv - ERRC;  // sound: s_fp32 + g <= s_bf16 + ERRC + g
  const float d = thr2 - s;
  const unsigned bits = tf2x32_xor(0u, (unsigned)R * 50000u + (unsigned)J);
  const float f = __uint_as_float((bits >> 9) | 0x3f800000u) - 1.0f;
  const float u = fmaxf(f, TINYF);
  const float thr_u = __expf(-__expf(-d)) * (1.0f - 2e-5f);
  if (u < thr_u) return;             // sound fast reject
  const float g = -logf(-logf(u));   // exact gumbel (rare path)
  if (s + g < thr2) return;          // exact tier-2
  const float4* hp = (const float4*)(hfin + (size_t)R * 128);
  const float4* ap = (const float4*)(items + (size_t)J * 128);
  float4 a4 = {0.f, 0.f, 0.f, 0.f};
#pragma unroll
  for (int k = 0; k < 32; ++k) {
    float4 h = hp[k];
    float4 b = ap[k];
    a4.x = fmaf(h.x, b.x, a4.x);
    a4.y = fmaf(h.y, b.y, a4.y);
    a4.z = fmaf(h.z, b.z, a4.z);
    a4.w = fmaf(h.w, b.w, a4.w);
  }
  const float v = ((a4.x + a4.y) + (a4.z + a4.w)) + g;
  const unsigned ov = ordf(v);
  if (ov >= hiw[2 * R + 1]) {  // '>=': let atomicMax resolve smaller-J ties
    const unsigned long long pk =
        ((unsigned long long)ov << 32) | (0xFFFFFFFFu - (unsigned)J);
    atomicMax(&rowslot[R], pk);
  }
}

// ---------------- h = x @ W + b (f64 accumulate) + workspace init ----------
__global__ void k_hraw(const float* __restrict__ x, const float* __restrict__ W,
                       const float* __restrict__ b, float* __restrict__ hraw,
                       unsigned long long* __restrict__ rowslot,
                       float* __restrict__ norms) {
  __shared__ float sx[256];
  const int i = blockIdx.x;
  const int d = threadIdx.x;  // 128 threads
  if (d == 0) {
    rowslot[i] = 0ull;
    if (i == 0) { norms[0] = 0.0f; norms[1] = 0.0f; }
  }
  sx[d] = x[i * 256 + d];
  sx[d + 128] = x[i * 256 + 128 + d];
  __syncthreads();
  double acc = 0.0;
  for (int k = 0; k < 256; ++k)
    acc = fma((double)sx[k], (double)W[k * 128 + d], acc);
  hraw[i * 128 + d] = (float)acc + b[d];
}

// ---- items fp32 -> bf16 (RNE, same bits) + max row-norm^2, one pass -------
// Launched AFTER k_hraw (stream order) so norms[1]=0 init precedes atomics.
__global__ void k_bca(const float* __restrict__ items,
                      unsigned short* __restrict__ ib,
                      float* __restrict__ norms) {
  __shared__ float red[4];
  const int t = threadIdx.x;
  const int row = blockIdx.x * 32 + (t >> 3);
  const int rc = row > 49999 ? 49999 : row;  // dup row: harmless for max
  const int c = (t & 7) * 16;
  const float4* p = (const float4*)(items + (size_t)rc * 128 + c);
  const float4 v0 = p[0], v1 = p[1], v2 = p[2], v3 = p[3];
  float ss = v0.x * v0.x + v0.y * v0.y + v0.z * v0.z + v0.w * v0.w +
             v1.x * v1.x + v1.y * v1.y + v1.z * v1.z + v1.w * v1.w +
             v2.x * v2.x + v2.y * v2.y + v2.z * v2.z + v2.w * v2.w +
             v3.x * v3.x + v3.y * v3.y + v3.z * v3.z + v3.w * v3.w;
  if (row <= 49999) {
    uint4 o0, o1;
    o0.x = pk2(v0.x, v0.y); o0.y = pk2(v0.z, v0.w);
    o0.z = pk2(v1.x, v1.y); o0.w = pk2(v1.z, v1.w);
    o1.x = pk2(v2.x, v2.y); o1.y = pk2(v2.z, v2.w);
    o1.z = pk2(v3.x, v3.y); o1.w = pk2(v3.z, v3.w);
    uint4* dst = (uint4*)(ib + (size_t)row * 128 + c);
    dst[0] = o0; dst[1] = o1;
  }
  ss += __shfl_xor(ss, 1);  // sum 8-lane row group
  ss += __shfl_xor(ss, 2);
  ss += __shfl_xor(ss, 4);
  ss = fmaxf(ss, __shfl_xor(ss, 8));   // max across rows in wave
  ss = fmaxf(ss, __shfl_xor(ss, 16));
  ss = fmaxf(ss, __shfl_xor(ss, 32));
  if ((t & 63) == 0) red[t >> 6] = ss;
  __syncthreads();
  if (t == 0) {
    float mx = fmaxf(fmaxf(red[0], red[1]), fmaxf(red[2], red[3]));
    atomicMax((unsigned*)&norms[1], __float_as_uint(mx));
  }
}

// ---------------- BN stats per column (f64) ----------------
__global__ void k_bnstats(const float* __restrict__ hraw,
                          float* __restrict__ meanv, float* __restrict__ rsv) {
  __shared__ double red[256];
  const int d = blockIdx.x;   // 128 blocks
  const int t = threadIdx.x;  // 256 threads
  double s = 0.0;
  for (int i = t; i < 2048; i += 256) s += (double)hraw[i * 128 + d];
  red[t] = s;
  __syncthreads();
  for (int off = 128; off > 0; off >>= 1) {
    if (t < off) red[t] += red[t + off];
    __syncthreads();
  }
  const float m = (float)(red[0] * (1.0 / 2048.0));
  __syncthreads();
  double v = 0.0;
  for (int i = t; i < 2048; i += 256) {
    float dd = __fsub_rn(hraw[i * 128 + d], m);
    v += (double)dd * (double)dd;
  }
  red[t] = v;
  __syncthreads();
  for (int off = 128; off > 0; off >>= 1) {
    if (t < off) red[t] += red[t + off];
    __syncthreads();
  }
  if (t == 0) {
    float var = (float)(red[0] * (1.0 / 2048.0));
    float vpe = __fadd_rn(var, 1e-5f);
    meanv[d] = m;
    rsv[d] = (float)(1.0 / sqrt((double)vpe));
  }
}

// ---------------- apply BN + leaky relu, emit bf16 copy + max row-norm ------
__global__ void k_apply(const float* __restrict__ hraw,
                        const float* __restrict__ meanv, const float* __restrict__ rsv,
                        const float* __restrict__ gamma, const float* __restrict__ beta,
                        float* __restrict__ hfin, unsigned short* __restrict__ hb,
                        float* __restrict__ norms) {
  __shared__ float red[256];
  const int t = threadIdx.x;
  const int idx = blockIdx.x * 256 + t;  // 2 rows per block
  const int d = idx & 127;
  float h = hraw[idx];
  float hn = __fadd_rn(__fmul_rn(__fmul_rn(__fsub_rn(h, meanv[d]), rsv[d]), gamma[d]), beta[d]);
  float o = (hn >= 0.0f) ? hn : __fmul_rn(0.01f, hn);
  hfin[idx] = o;
  hb[idx] = f2bf(o);
  red[t] = o * o;
  __syncthreads();
  for (int off = 64; off > 0; off >>= 1) {
    if ((t & 127) < off) red[t] += red[t + off];
    __syncthreads();
  }
  if ((t & 127) == 0) atomicMax((unsigned*)&norms[0], __float_as_uint(red[t]));
}

// ---------------- bf16 MFMA screen: ZERO-barrier wave-private pipeline -----
// Round 15 structure (zero __syncthreads, wave-private 2x4KB LDS dbuf,
// counted vmcnt, ballot queues) with two deltas:
//  1. NO k_seed / V0: thresholds self-seed from rowslot (-inf start). Iter-0
//     resolves its 16 j per row (what k_seed did, but on L2-hot staged data,
//     shared across the 64 concurrent spans per row). Saves the ~35us
//     512B-strided k_seed kernel + a launch.
//  2. MFMA dependent chain split into two accumulators (kb 0,2 / 1,3),
//     summed at the end: ~60cyc less serial latency per iter. Order change
//     is inside the ERRC bound; final scores stay exact fp32.
__global__ __launch_bounds__(256, 2) void k_screen(
    const unsigned short* __restrict__ hb, const float* __restrict__ hfin,
    const float* __restrict__ items, const unsigned short* __restrict__ ib,
    const float* __restrict__ norms, unsigned long long* __restrict__ rowslot) {
  __shared__ __align__(16) unsigned short Bs[4][2][16 * 128];  // 32KB
  __shared__ unsigned qk[4][128];  // per-wave candidate queues
  __shared__ float qsh[4][128];

  const int t = threadIdx.x;
  const int w = t >> 6, l = t & 63;
  const int lg = l >> 4, lr = l & 15;
  const int rg = blockIdx.x >> 6;       // 0..31
  const int span = blockIdx.x & 63;
  const int r0w = rg * 64 + w * 16;     // this wave's 16 rows
  const int tile0 = span * SPT16;
  int nt = NT16 - tile0;
  nt = nt < 0 ? 0 : (nt > SPT16 ? SPT16 : nt);
  if (nt == 0) return;  // block-uniform (span 63 has 38)

  const float ERRC = 0.004f * sqrtf(norms[0] * norms[1]) + 0.01f;
  const volatile unsigned* hiw = (const volatile unsigned*)rowslot;  // hi @ 2R+1

  // resident A fragments: lane holds row (r0w + lr), 8 k each
  const unsigned short* aB0 = hb + (size_t)(r0w + lr) * 128 + lg * 8;
  bf16x8 Afrag[4];
#pragma unroll
  for (int kb = 0; kb < 4; ++kb) Afrag[kb] = *(const bf16x8*)(aB0 + kb * 32);

  // wave-private staging: chunk c covers LDS bytes [c*1024, +1024);
  // lane l -> LDS off c*1024 + l*16; tile-local row = c*4 + (l>>4),
  // col = (l&15)*16; swizzled global col = col ^ ((row&7)<<4).
  char* wlds = (char*)Bs + w * 8192;
  const char* ibc = (const char*)ib;
  int so[4];
#pragma unroll
  for (int c = 0; c < 4; ++c) {
    const int row = c * 4 + (l >> 4);
    const int col = (l & 15) * 16;
    so[c] = row * 256 + (col ^ ((row & 7) << 4));
  }

#define ISSUE(tl, pbuf)                                                        \
  {                                                                            \
    const char* gs = ibc + (size_t)(tl) * 4096;                                \
    char* ld = wlds + (pbuf) * 4096;                                           \
    __builtin_amdgcn_global_load_lds((const unsigned*)(gs + so[0]),            \
                                     (unsigned*)(ld), 16, 0, 0);               \
    __builtin_amdgcn_global_load_lds((const unsigned*)(gs + so[1]),            \
                                     (unsigned*)(ld + 1024), 16, 0, 0);        \
    __builtin_amdgcn_global_load_lds((const unsigned*)(gs + so[2]),            \
                                     (unsigned*)(ld + 2048), 16, 0, 0);        \
    __builtin_amdgcn_global_load_lds((const unsigned*)(gs + so[3]),            \
                                     (unsigned*)(ld + 3072), 16, 0, 0);        \
  }
#define WAITVM4() { asm volatile("s_waitcnt vmcnt(4)" ::: "memory"); \
                    __builtin_amdgcn_sched_barrier(0); }
#define WAITVM0() { asm volatile("s_waitcnt vmcnt(0)" ::: "memory"); \
                    __builtin_amdgcn_sched_barrier(0); }

  // prologue: stage tile0 -> buf 0
  ISSUE(tile0, 0)

  const unsigned long long lml = (1ull << l) - 1ull;  // lanes below me
  unsigned qn = 0;     // wave-uniform queue count (SGPR)
  float th1[4];        // tier-1 thresholds (registers)

  int pb = 0;
  for (int it = 0; it < nt; ++it) {
    const int j0 = (tile0 + it) * 16;

    // ---- issue next tile; counted wait retires ONLY the current tile ----
    if (it + 1 < nt) {
      ISSUE(tile0 + it + 1, pb ^ 1)
      WAITVM4()
    } else {
      WAITVM0()
    }

    // ---- refresh tier-1 thresholds every 8 tiles (stale-low is safe) ----
    if ((it & 7) == 0) {
      float tvl = -3.4e38f;
      if (l < 16) {
        const unsigned hi = hiw[2 * (r0w + l) + 1];
        if (hi) tvl = unordf(hi);
      }
#pragma unroll
      for (int q = 0; q < 4; ++q)
        th1[q] = __shfl(tvl, lg * 4 + q) - GMAX - ERRC;
    }

    // ---- 4 ds_read + 4 MFMA (two independent chains) from buf pb ----
    f32x4 a0 = (f32x4){0.f, 0.f, 0.f, 0.f};
    f32x4 a1 = (f32x4){0.f, 0.f, 0.f, 0.f};
    const char* tb = wlds + pb * 4096;
    {
      bf16x8 b0 = *(const bf16x8*)(tb + bswz(lr * 256 + 0 * 64 + lg * 16));
      bf16x8 b1 = *(const bf16x8*)(tb + bswz(lr * 256 + 1 * 64 + lg * 16));
      bf16x8 b2 = *(const bf16x8*)(tb + bswz(lr * 256 + 2 * 64 + lg * 16));
      bf16x8 b3 = *(const bf16x8*)(tb + bswz(lr * 256 + 3 * 64 + lg * 16));
      a0 = __builtin_amdgcn_mfma_f32_16x16x32_bf16(Afrag[0], b0, a0, 0, 0, 0);
      a1 = __builtin_amdgcn_mfma_f32_16x16x32_bf16(Afrag[1], b1, a1, 0, 0, 0);
      a0 = __builtin_amdgcn_mfma_f32_16x16x32_bf16(Afrag[2], b2, a0, 0, 0, 0);
      a1 = __builtin_amdgcn_mfma_f32_16x16x32_bf16(Afrag[3], b3, a1, 0, 0, 0);
    }
    const f32x4 acc = a0 + a1;

    // ---- tier-1 push via ballot compaction; per-wave drain at >=64 ----
    // C/D layout: col = lane&15 (lr) -> J = j0+lr; row = (lane>>4)*4 + q.
#pragma unroll
    for (int q = 0; q < 4; ++q) {
      const float s = acc[q];
      const int J = j0 + lr;
      const bool c = (s >= th1[q]);
      const unsigned long long m = __ballot(c);
      if (m) {
        if (c) {
          const unsigned idx = qn + (unsigned)__popcll(m & lml);
          qk[w][idx] = ((unsigned)(lg * 4 + q) << 16) | (unsigned)J;
          qsh[w][idx] = s;
        }
        qn += (unsigned)__popcll(m);
        if (qn >= 64) {  // drain fully (qn <= 127 -> fits cap 128)
          for (unsigned i = (unsigned)l; i < qn; i += 64) {
            const unsigned key = qk[w][i];
            resolve_cand(r0w + (int)(key >> 16), (int)(key & 0xFFFFu),
                         qsh[w][i], ERRC, hfin, items, rowslot, hiw);
          }
          qn = 0;
        }
      }
    }

    pb ^= 1;
  }

  // ---- final drain ----
  for (unsigned i = (unsigned)l; i < qn; i += 64) {
    const unsigned key = qk[w][i];
    resolve_cand(r0w + (int)(key >> 16), (int)(key & 0xFFFFu),
                 qsh[w][i], ERRC, hfin, items, rowslot, hiw);
  }
#undef ISSUE
#undef WAITVM4
#undef WAITVM0
}

// ---------------- final: read row winner + cosine sim (one wave/row) -------
__global__ void k_final(const unsigned long long* __restrict__ rowslot,
                        const int* __restrict__ uid, const float* __restrict__ items,
                        float* __restrict__ dout, float* __restrict__ simv) {
  const int r = blockIdx.x;
  const int lane = threadIdx.x;  // 64
  const unsigned long long pk = rowslot[r];  // nonzero: winner always resolves
  const int bi = (int)(0xFFFFFFFFu - (unsigned)pk);
  if (lane == 0) dout[r] = (float)bi;

  const int orig = uid[r * 2 + 1];
  float o1 = items[(size_t)orig * 128 + lane];
  float o2 = items[(size_t)orig * 128 + 64 + lane];
  float p1 = items[(size_t)bi * 128 + lane];
  float p2 = items[(size_t)bi * 128 + 64 + lane];
  float d = o1 * p1 + o2 * p2;
  float s1 = o1 * o1 + o2 * o2;
  float s2 = p1 * p1 + p2 * p2;
  for (int off = 32; off > 0; off >>= 1) {
    d += __shfl_down(d, off);
    s1 += __shfl_down(s1, off);
    s2 += __shfl_down(s2, off);
  }
  if (lane == 0) {
    float n1 = fmaxf(sqrtf(s1), 1e-6f);
    float n2 = fmaxf(sqrtf(s2), 1e-6f);
    float sim = d / (n1 * n2);
    simv[r] = (sim + 1.0f) * 0.5f;
  }
}

// ---------------- final scalar reductions ----------------
__global__ void k_reduce(const float* __restrict__ simv, float* __restrict__ dout) {
  __shared__ double rl[256];
  __shared__ double rs[256];
  const int t = threadIdx.x;
  double L = 0.0, S = 0.0;
  for (int i = t; i < 2048; i += 256) {
    double s = (double)simv[i];
    double dd = s - 0.5;
    L += dd * dd;
    S += s;
  }
  rl[t] = L; rs[t] = S;
  __syncthreads();
  for (int off = 128; off > 0; off >>= 1) {
    if (t < off) { rl[t] += rl[t + off]; rs[t] += rs[t + off]; }
    __syncthreads();
  }
  if (t == 0) {
    dout[2048] = (float)(rl[0] * (1.0 / 2048.0));
    dout[2049] = (float)(rs[0] * (1.0 / 2048.0));
  }
}

extern "C" void kernel_launch(void* const* d_in, const int* in_sizes, int n_in,
                              void* d_out, int out_size, void* d_ws, size_t ws_size,
                              hipStream_t stream) {
  const int* uid = (const int*)d_in[0];       // (2048,2) int32
  const float* xfeat = (const float*)d_in[1]; // (2048,256)
  const float* items = (const float*)d_in[2]; // (50000,128)
  const float* W = (const float*)d_in[3];     // (256,128)
  const float* bias = (const float*)d_in[4];  // (128,)
  const float* gamma = (const float*)d_in[5]; // (128,)
  const float* beta = (const float*)d_in[6];  // (128,)

  float* ws = (float*)d_ws;
  float* hraw = ws;                                   // 262144 f
  float* hfin = ws + 262144;                          // 262144 f
  float* meanv = ws + 524288;                         // 128 f
  float* rsv = ws + 524416;                           // 128 f
  float* simv = ws + 526592;                          // 2048 f
  float* norms = ws + 528640;                         // 2 f (Hmax^2, Amax^2)
  unsigned long long* rowslot =
      (unsigned long long*)(ws + 528642);             // 2048 u64 (8B aligned)
  unsigned short* hb = (unsigned short*)(ws + 532740); // 262144 bf16
  unsigned short* ib = (unsigned short*)(ws + 663812); // 12.8MB bf16 (16B aligned)
  float* dout = (float*)d_out;                        // 2050 floats

  hipLaunchKernelGGL(k_hraw, dim3(2048), dim3(128), 0, stream, xfeat, W, bias, hraw, rowslot, norms);
  hipLaunchKernelGGL(k_bca, dim3(1563), dim3(256), 0, stream, items, ib, norms);
  hipLaunchKernelGGL(k_bnstats, dim3(128), dim3(256), 0, stream, hraw, meanv, rsv);
  hipLaunchKernelGGL(k_apply, dim3(1024), dim3(256), 0, stream, hraw, meanv, rsv, gamma, beta, hfin, hb, norms);
  hipLaunchKernelGGL(k_screen, dim3(2048), dim3(256), 0, stream, hb, hfin, items, ib, norms, rowslot);
  hipLaunchKernelGGL(k_final, dim3(2048), dim3(64), 0, stream, rowslot, uid, items, dout, simv);
  hipLaunchKernelGGL(k_reduce, dim3(1), dim3(256), 0, stream, simv, dout);
}

// Round 17
// 356.379 us; speedup vs baseline: 1.6311x; 1.6311x over previous
//
#include <hip/hip_runtime.h>
#include <math.h>

#define TINYF 1.17549435e-38f
#define GMAX 16.0f   // hard upper bound on gumbel (15.9424) + slack
#define NT16 3125    // 50000 / 16 exactly
#define SPT16 49     // tiles per span (64 spans x 49 >= 3125)

typedef __attribute__((ext_vector_type(8))) short bf16x8;
typedef __attribute__((ext_vector_type(4))) float f32x4;

// ---------------- threefry2x32, key = (0, 42) ----------------
__device__ __forceinline__ unsigned rotl32(unsigned x, int r) {
  return (x << r) | (x >> (32 - r));
}

__device__ __forceinline__ unsigned tf2x32_xor(unsigned x0, unsigned x1) {
  const unsigned k0 = 0u, k1 = 42u, k2 = 0x1BD11BF0u;  // 0x1BD11BDA ^ 0 ^ 42
  x0 += k0; x1 += k1;
#define TFR(r) { x0 += x1; x1 = rotl32(x1, r); x1 ^= x0; }
  TFR(13) TFR(15) TFR(26) TFR(6)
  x0 += k1; x1 += k2 + 1u;
  TFR(17) TFR(29) TFR(16) TFR(24)
  x0 += k2; x1 += k0 + 2u;
  TFR(13) TFR(15) TFR(26) TFR(6)
  x0 += k0; x1 += k1 + 3u;
  TFR(17) TFR(29) TFR(16) TFR(24)
  x0 += k1; x1 += k2 + 4u;
  TFR(13) TFR(15) TFR(26) TFR(6)
  x0 += k2; x1 += k0 + 5u;
#undef TFR
  return x0 ^ x1;
}

__device__ __forceinline__ float gumbel_from_bits(unsigned bits) {
  float f = __uint_as_float((bits >> 9) | 0x3f800000u) - 1.0f;
  float u = fmaxf(f, TINYF);
  return -logf(-logf(u));
}

// order-preserving float->uint (monotone)
__device__ __forceinline__ unsigned ordf(float v) {
  unsigned b = __float_as_uint(v);
  return (b & 0x80000000u) ? ~b : (b | 0x80000000u);
}
__device__ __forceinline__ float unordf(unsigned u) {
  unsigned b = (u & 0x80000000u) ? (u & 0x7FFFFFFFu) : ~u;
  return __uint_as_float(b);
}

// fp32 -> bf16 RNE (bit trick)
__device__ __forceinline__ unsigned short f2bf(float f) {
  unsigned u = __float_as_uint(f);
  unsigned r = u + 0x7FFFu + ((u >> 16) & 1u);
  return (unsigned short)(r >> 16);
}
__device__ __forceinline__ unsigned pk2(float a, float b) {
  return (unsigned)f2bf(a) | ((unsigned)f2bf(b) << 16);
}
// XOR swizzle within a 16-row x 256B tile (kills stride-256B bank conflicts)
__device__ __forceinline__ int bswz(int b) { return b ^ (((b >> 8) & 7) << 4); }

// ---- candidate resolution. Tier-2 threshold from max(V0u, rowslot) --
// fresh + monotone. Fast u-space pre-test with HW exp (no false reject;
// ~2e-5 over-accept filtered by the exact path). ONE noinline copy.
__device__ __attribute__((noinline)) void resolve_cand(
    int R, int J, float s, float ERRC,
    const float* __restrict__ hfin, const float* __restrict__ items,
    const unsigned* __restrict__ V0u,
    unsigned long long* __restrict__ rowslot, const volatile unsigned* hiw) {
  const unsigned v0 = V0u[R];
  const unsigned hi0 = hiw[2 * R + 1];
  float tv = v0 ? unordf(v0) : -3.4e38f;
  if (hi0) tv = fmaxf(tv, unordf(hi0));
  const float thr2 = tv - ERRC;  // sound: s_fp32 + g <= s_bf16 + ERRC + g
  const float d = thr2 - s;
  const unsigned bits = tf2x32_xor(0u, (unsigned)R * 50000u + (unsigned)J);
  const float f = __uint_as_float((bits >> 9) | 0x3f800000u) - 1.0f;
  const float u = fmaxf(f, TINYF);
  const float thr_u = __expf(-__expf(-d)) * (1.0f - 2e-5f);
  if (u < thr_u) return;             // sound fast reject
  const float g = -logf(-logf(u));   // exact gumbel (rare path)
  if (s + g < thr2) return;          // exact tier-2
  const float4* hp = (const float4*)(hfin + (size_t)R * 128);
  const float4* ap = (const float4*)(items + (size_t)J * 128);
  float4 a4 = {0.f, 0.f, 0.f, 0.f};
#pragma unroll
  for (int k = 0; k < 32; ++k) {
    float4 h = hp[k];
    float4 b = ap[k];
    a4.x = fmaf(h.x, b.x, a4.x);
    a4.y = fmaf(h.y, b.y, a4.y);
    a4.z = fmaf(h.z, b.z, a4.z);
    a4.w = fmaf(h.w, b.w, a4.w);
  }
  const float v = ((a4.x + a4.y) + (a4.z + a4.w)) + g;
  const unsigned ov = ordf(v);
  if (ov >= hiw[2 * R + 1]) {  // '>=': let atomicMax resolve smaller-J ties
    const unsigned long long pk =
        ((unsigned long long)ov << 32) | (0xFFFFFFFFu - (unsigned)J);
    atomicMax(&rowslot[R], pk);
  }
}

// ---------------- h = x @ W + b (f64 accumulate) + workspace init ----------
__global__ void k_hraw(const float* __restrict__ x, const float* __restrict__ W,
                       const float* __restrict__ b, float* __restrict__ hraw,
                       unsigned long long* __restrict__ rowslot,
                       unsigned* __restrict__ V0u, float* __restrict__ norms) {
  __shared__ float sx[256];
  const int i = blockIdx.x;
  const int d = threadIdx.x;  // 128 threads
  if (d == 0) {
    rowslot[i] = 0ull;
    V0u[i] = 0u;
    if (i == 0) { norms[0] = 0.0f; norms[1] = 0.0f; }
  }
  sx[d] = x[i * 256 + d];
  sx[d + 128] = x[i * 256 + 128 + d];
  __syncthreads();
  double acc = 0.0;
  for (int k = 0; k < 256; ++k)
    acc = fma((double)sx[k], (double)W[k * 128 + d], acc);
  hraw[i * 128 + d] = (float)acc + b[d];
}

// ---- items fp32 -> bf16 (RNE, same bits) + max row-norm^2, one pass -------
// Launched AFTER k_hraw (stream order) so norms[1]=0 init precedes atomics.
__global__ void k_bca(const float* __restrict__ items,
                      unsigned short* __restrict__ ib,
                      float* __restrict__ norms) {
  __shared__ float red[4];
  const int t = threadIdx.x;
  const int row = blockIdx.x * 32 + (t >> 3);
  const int rc = row > 49999 ? 49999 : row;  // dup row: harmless for max
  const int c = (t & 7) * 16;
  const float4* p = (const float4*)(items + (size_t)rc * 128 + c);
  const float4 v0 = p[0], v1 = p[1], v2 = p[2], v3 = p[3];
  float ss = v0.x * v0.x + v0.y * v0.y + v0.z * v0.z + v0.w * v0.w +
             v1.x * v1.x + v1.y * v1.y + v1.z * v1.z + v1.w * v1.w +
             v2.x * v2.x + v2.y * v2.y + v2.z * v2.z + v2.w * v2.w +
             v3.x * v3.x + v3.y * v3.y + v3.z * v3.z + v3.w * v3.w;
  if (row <= 49999) {
    uint4 o0, o1;
    o0.x = pk2(v0.x, v0.y); o0.y = pk2(v0.z, v0.w);
    o0.z = pk2(v1.x, v1.y); o0.w = pk2(v1.z, v1.w);
    o1.x = pk2(v2.x, v2.y); o1.y = pk2(v2.z, v2.w);
    o1.z = pk2(v3.x, v3.y); o1.w = pk2(v3.z, v3.w);
    uint4* dst = (uint4*)(ib + (size_t)row * 128 + c);
    dst[0] = o0; dst[1] = o1;
  }
  ss += __shfl_xor(ss, 1);  // sum 8-lane row group
  ss += __shfl_xor(ss, 2);
  ss += __shfl_xor(ss, 4);
  ss = fmaxf(ss, __shfl_xor(ss, 8));   // max across rows in wave
  ss = fmaxf(ss, __shfl_xor(ss, 16));
  ss = fmaxf(ss, __shfl_xor(ss, 32));
  if ((t & 63) == 0) red[t >> 6] = ss;
  __syncthreads();
  if (t == 0) {
    float mx = fmaxf(fmaxf(red[0], red[1]), fmaxf(red[2], red[3]));
    atomicMax((unsigned*)&norms[1], __float_as_uint(mx));
  }
}

// ---------------- BN stats per column (f64) ----------------
__global__ void k_bnstats(const float* __restrict__ hraw,
                          float* __restrict__ meanv, float* __restrict__ rsv) {
  __shared__ double red[256];
  const int d = blockIdx.x;   // 128 blocks
  const int t = threadIdx.x;  // 256 threads
  double s = 0.0;
  for (int i = t; i < 2048; i += 256) s += (double)hraw[i * 128 + d];
  red[t] = s;
  __syncthreads();
  for (int off = 128; off > 0; off >>= 1) {
    if (t < off) red[t] += red[t + off];
    __syncthreads();
  }
  const float m = (float)(red[0] * (1.0 / 2048.0));
  __syncthreads();
  double v = 0.0;
  for (int i = t; i < 2048; i += 256) {
    float dd = __fsub_rn(hraw[i * 128 + d], m);
    v += (double)dd * (double)dd;
  }
  red[t] = v;
  __syncthreads();
  for (int off = 128; off > 0; off >>= 1) {
    if (t < off) red[t] += red[t + off];
    __syncthreads();
  }
  if (t == 0) {
    float var = (float)(red[0] * (1.0 / 2048.0));
    float vpe = __fadd_rn(var, 1e-5f);
    meanv[d] = m;
    rsv[d] = (float)(1.0 / sqrt((double)vpe));
  }
}

// ---------------- apply BN + leaky relu, emit bf16 copy + max row-norm ------
__global__ void k_apply(const float* __restrict__ hraw,
                        const float* __restrict__ meanv, const float* __restrict__ rsv,
                        const float* __restrict__ gamma, const float* __restrict__ beta,
                        float* __restrict__ hfin, unsigned short* __restrict__ hb,
                        float* __restrict__ norms) {
  __shared__ float red[256];
  const int t = threadIdx.x;
  const int idx = blockIdx.x * 256 + t;  // 2 rows per block
  const int d = idx & 127;
  float h = hraw[idx];
  float hn = __fadd_rn(__fmul_rn(__fmul_rn(__fsub_rn(h, meanv[d]), rsv[d]), gamma[d]), beta[d]);
  float o = (hn >= 0.0f) ? hn : __fmul_rn(0.01f, hn);
  hfin[idx] = o;
  hb[idx] = f2bf(o);
  red[t] = o * o;
  __syncthreads();
  for (int off = 64; off > 0; off >>= 1) {
    if ((t & 127) < off) red[t] += red[t + off];
    __syncthreads();
  }
  if ((t & 127) == 0) atomicMax((unsigned*)&norms[0], __float_as_uint(red[t]));
}

// ---------------- V0 seed via MFMA: lower bound on max_{j<1024}(s+g) -------
// grid 256 = rg*8 + jspan (rg 0..31, jspan 0..7). 4 waves x 16 rows, each
// covering 128 j (8 tiles of 16). Same fragment layout as k_screen; B-frags
// direct from ib (L2-hot). v = s_bf16 + g; per-row max via 16-lane shfl
// butterfly; atomicMax(V0u[R], ordf(vmax - ERRC)). Sound lower bound:
// s_fp32 >= s_bf16 - ERRC pointwise. rowslot keeps exact values only.
// Replaces the old scalar-FMA k_seed (~35us, 512B-strided loads).
__global__ __launch_bounds__(256, 2) void k_seed(
    const unsigned short* __restrict__ hb, const unsigned short* __restrict__ ib,
    const float* __restrict__ norms, unsigned* __restrict__ V0u) {
  const int t = threadIdx.x;
  const int w = t >> 6, l = t & 63;
  const int lg = l >> 4, lr = l & 15;
  const int rg = blockIdx.x >> 3;     // 0..31
  const int jspan = blockIdx.x & 7;   // 0..7
  const int r0w = rg * 64 + w * 16;
  const float ERRC = 0.004f * sqrtf(norms[0] * norms[1]) + 0.01f;

  const unsigned short* aB0 = hb + (size_t)(r0w + lr) * 128 + lg * 8;
  bf16x8 Afrag[4];
#pragma unroll
  for (int kb = 0; kb < 4; ++kb) Afrag[kb] = *(const bf16x8*)(aB0 + kb * 32);

  float vmax[4] = {-3.4e38f, -3.4e38f, -3.4e38f, -3.4e38f};
  for (int itr = 0; itr < 8; ++itr) {
    const int J = jspan * 128 + itr * 16 + lr;
    const unsigned short* bp = ib + (size_t)J * 128 + lg * 8;
    f32x4 acc = (f32x4){0.f, 0.f, 0.f, 0.f};
#pragma unroll
    for (int kb = 0; kb < 4; ++kb)
      acc = __builtin_amdgcn_mfma_f32_16x16x32_bf16(Afrag[kb], *(const bf16x8*)(bp + kb * 32), acc, 0, 0, 0);
#pragma unroll
    for (int q = 0; q < 4; ++q) {
      const int R = r0w + lg * 4 + q;
      const float g = gumbel_from_bits(tf2x32_xor(0u, (unsigned)R * 50000u + (unsigned)J));
      vmax[q] = fmaxf(vmax[q], acc[q] + g);
    }
  }
#pragma unroll
  for (int m = 1; m <= 8; m <<= 1)
#pragma unroll
    for (int q = 0; q < 4; ++q) vmax[q] = fmaxf(vmax[q], __shfl_xor(vmax[q], m));
  if (lr == 0) {
#pragma unroll
    for (int q = 0; q < 4; ++q)
      atomicMax(&V0u[r0w + lg * 4 + q], ordf(vmax[q] - ERRC));
  }
}

// ---------------- bf16 MFMA screen: ZERO-barrier wave-private pipeline -----
// Round 15 structure verbatim (zero __syncthreads, wave-private 2x4KB LDS
// dbuf, counted vmcnt, ballot queues, V0-seeded thresholds) + the MFMA
// chain split into two accumulators (order change inside the ERRC bound).
__global__ __launch_bounds__(256, 2) void k_screen(
    const unsigned short* __restrict__ hb, const float* __restrict__ hfin,
    const float* __restrict__ items, const unsigned short* __restrict__ ib,
    const unsigned* __restrict__ V0u,
    const float* __restrict__ norms, unsigned long long* __restrict__ rowslot) {
  __shared__ __align__(16) unsigned short Bs[4][2][16 * 128];  // 32KB
  __shared__ unsigned qk[4][128];  // per-wave candidate queues
  __shared__ float qsh[4][128];

  const int t = threadIdx.x;
  const int w = t >> 6, l = t & 63;
  const int lg = l >> 4, lr = l & 15;
  const int rg = blockIdx.x >> 6;       // 0..31
  const int span = blockIdx.x & 63;
  const int r0w = rg * 64 + w * 16;     // this wave's 16 rows
  const int tile0 = span * SPT16;
  int nt = NT16 - tile0;
  nt = nt < 0 ? 0 : (nt > SPT16 ? SPT16 : nt);
  if (nt == 0) return;  // block-uniform (span 63 has 38)

  const float ERRC = 0.004f * sqrtf(norms[0] * norms[1]) + 0.01f;
  const volatile unsigned* hiw = (const volatile unsigned*)rowslot;  // hi @ 2R+1

  // resident A fragments: lane holds row (r0w + lr), 8 k each
  const unsigned short* aB0 = hb + (size_t)(r0w + lr) * 128 + lg * 8;
  bf16x8 Afrag[4];
#pragma unroll
  for (int kb = 0; kb < 4; ++kb) Afrag[kb] = *(const bf16x8*)(aB0 + kb * 32);

  // wave-private staging: chunk c covers LDS bytes [c*1024, +1024);
  // lane l -> LDS off c*1024 + l*16; tile-local row = c*4 + (l>>4),
  // col = (l&15)*16; swizzled global col = col ^ ((row&7)<<4).
  char* wlds = (char*)Bs + w * 8192;
  const char* ibc = (const char*)ib;
  int so[4];
#pragma unroll
  for (int c = 0; c < 4; ++c) {
    const int row = c * 4 + (l >> 4);
    const int col = (l & 15) * 16;
    so[c] = row * 256 + (col ^ ((row & 7) << 4));
  }

#define ISSUE(tl, pbuf)                                                        \
  {                                                                            \
    const char* gs = ibc + (size_t)(tl) * 4096;                                \
    char* ld = wlds + (pbuf) * 4096;                                           \
    __builtin_amdgcn_global_load_lds((const unsigned*)(gs + so[0]),            \
                                     (unsigned*)(ld), 16, 0, 0);               \
    __builtin_amdgcn_global_load_lds((const unsigned*)(gs + so[1]),            \
                                     (unsigned*)(ld + 1024), 16, 0, 0);        \
    __builtin_amdgcn_global_load_lds((const unsigned*)(gs + so[2]),            \
                                     (unsigned*)(ld + 2048), 16, 0, 0);        \
    __builtin_amdgcn_global_load_lds((const unsigned*)(gs + so[3]),            \
                                     (unsigned*)(ld + 3072), 16, 0, 0);        \
  }
#define WAITVM4() { asm volatile("s_waitcnt vmcnt(4)" ::: "memory"); \
                    __builtin_amdgcn_sched_barrier(0); }
#define WAITVM0() { asm volatile("s_waitcnt vmcnt(0)" ::: "memory"); \
                    __builtin_amdgcn_sched_barrier(0); }

  // prologue: stage tile0 -> buf 0
  ISSUE(tile0, 0)

  const unsigned long long lml = (1ull << l) - 1ull;  // lanes below me
  unsigned qn = 0;     // wave-uniform queue count (SGPR)
  float th1[4];        // tier-1 thresholds (registers)

  int pb = 0;
  for (int it = 0; it < nt; ++it) {
    const int j0 = (tile0 + it) * 16;

    // ---- issue next tile; counted wait retires ONLY the current tile ----
    if (it + 1 < nt) {
      ISSUE(tile0 + it + 1, pb ^ 1)
      WAITVM4()
    } else {
      WAITVM0()
    }

    // ---- refresh tier-1 thresholds every 8 tiles (stale-low is safe) ----
    if ((it & 7) == 0) {
      float tvl = -3.4e38f;
      if (l < 16) {
        const int R = r0w + l;
        const unsigned v0 = V0u[R];
        if (v0) tvl = unordf(v0);
        const unsigned hi = hiw[2 * R + 1];
        if (hi) tvl = fmaxf(tvl, unordf(hi));
      }
#pragma unroll
      for (int q = 0; q < 4; ++q)
        th1[q] = __shfl(tvl, lg * 4 + q) - GMAX - ERRC;
    }

    // ---- 4 ds_read + 4 MFMA (two independent chains) from buf pb ----
    f32x4 a0 = (f32x4){0.f, 0.f, 0.f, 0.f};
    f32x4 a1 = (f32x4){0.f, 0.f, 0.f, 0.f};
    const char* tb = wlds + pb * 4096;
    {
      bf16x8 b0 = *(const bf16x8*)(tb + bswz(lr * 256 + 0 * 64 + lg * 16));
      bf16x8 b1 = *(const bf16x8*)(tb + bswz(lr * 256 + 1 * 64 + lg * 16));
      bf16x8 b2 = *(const bf16x8*)(tb + bswz(lr * 256 + 2 * 64 + lg * 16));
      bf16x8 b3 = *(const bf16x8*)(tb + bswz(lr * 256 + 3 * 64 + lg * 16));
      a0 = __builtin_amdgcn_mfma_f32_16x16x32_bf16(Afrag[0], b0, a0, 0, 0, 0);
      a1 = __builtin_amdgcn_mfma_f32_16x16x32_bf16(Afrag[1], b1, a1, 0, 0, 0);
      a0 = __builtin_amdgcn_mfma_f32_16x16x32_bf16(Afrag[2], b2, a0, 0, 0, 0);
      a1 = __builtin_amdgcn_mfma_f32_16x16x32_bf16(Afrag[3], b3, a1, 0, 0, 0);
    }
    const f32x4 acc = a0 + a1;

    // ---- tier-1 push via ballot compaction; per-wave drain at >=64 ----
    // C/D layout: col = lane&15 (lr) -> J = j0+lr; row = (lane>>4)*4 + q.
#pragma unroll
    for (int q = 0; q < 4; ++q) {
      const float s = acc[q];
      const int J = j0 + lr;
      const bool c = (s >= th1[q]);
      const unsigned long long m = __ballot(c);
      if (m) {
        if (c) {
          const unsigned idx = qn + (unsigned)__popcll(m & lml);
          qk[w][idx] = ((unsigned)(lg * 4 + q) << 16) | (unsigned)J;
          qsh[w][idx] = s;
        }
        qn += (unsigned)__popcll(m);
        if (qn >= 64) {  // drain fully (qn <= 127 -> fits cap 128)
          for (unsigned i = (unsigned)l; i < qn; i += 64) {
            const unsigned key = qk[w][i];
            resolve_cand(r0w + (int)(key >> 16), (int)(key & 0xFFFFu),
                         qsh[w][i], ERRC, hfin, items, V0u, rowslot, hiw);
          }
          qn = 0;
        }
      }
    }

    pb ^= 1;
  }

  // ---- final drain ----
  for (unsigned i = (unsigned)l; i < qn; i += 64) {
    const unsigned key = qk[w][i];
    resolve_cand(r0w + (int)(key >> 16), (int)(key & 0xFFFFu),
                 qsh[w][i], ERRC, hfin, items, V0u, rowslot, hiw);
  }
#undef ISSUE
#undef WAITVM4
#undef WAITVM0
}

// ---------------- final: read row winner + cosine sim (one wave/row) -------
__global__ void k_final(const unsigned long long* __restrict__ rowslot,
                        const int* __restrict__ uid, const float* __restrict__ items,
                        float* __restrict__ dout, float* __restrict__ simv) {
  const int r = blockIdx.x;
  const int lane = threadIdx.x;  // 64
  const unsigned long long pk = rowslot[r];  // nonzero: winner always resolves
  const int bi = (int)(0xFFFFFFFFu - (unsigned)pk);
  if (lane == 0) dout[r] = (float)bi;

  const int orig = uid[r * 2 + 1];
  float o1 = items[(size_t)orig * 128 + lane];
  float o2 = items[(size_t)orig * 128 + 64 + lane];
  float p1 = items[(size_t)bi * 128 + lane];
  float p2 = items[(size_t)bi * 128 + 64 + lane];
  float d = o1 * p1 + o2 * p2;
  float s1 = o1 * o1 + o2 * o2;
  float s2 = p1 * p1 + p2 * p2;
  for (int off = 32; off > 0; off >>= 1) {
    d += __shfl_down(d, off);
    s1 += __shfl_down(s1, off);
    s2 += __shfl_down(s2, off);
  }
  if (lane == 0) {
    float n1 = fmaxf(sqrtf(s1), 1e-6f);
    float n2 = fmaxf(sqrtf(s2), 1e-6f);
    float sim = d / (n1 * n2);
    simv[r] = (sim + 1.0f) * 0.5f;
  }
}

// ---------------- final scalar reductions ----------------
__global__ void k_reduce(const float* __restrict__ simv, float* __restrict__ dout) {
  __shared__ double rl[256];
  __shared__ double rs[256];
  const int t = threadIdx.x;
  double L = 0.0, S = 0.0;
  for (int i = t; i < 2048; i += 256) {
    double s = (double)simv[i];
    double dd = s - 0.5;
    L += dd * dd;
    S += s;
  }
  rl[t] = L; rs[t] = S;
  __syncthreads();
  for (int off = 128; off > 0; off >>= 1) {
    if (t < off) { rl[t] += rl[t + off]; rs[t] += rs[t + off]; }
    __syncthreads();
  }
  if (t == 0) {
    dout[2048] = (float)(rl[0] * (1.0 / 2048.0));
    dout[2049] = (float)(rs[0] * (1.0 / 2048.0));
  }
}

extern "C" void kernel_launch(void* const* d_in, const int* in_sizes, int n_in,
                              void* d_out, int out_size, void* d_ws, size_t ws_size,
                              hipStream_t stream) {
  const int* uid = (const int*)d_in[0];       // (2048,2) int32
  const float* xfeat = (const float*)d_in[1]; // (2048,256)
  const float* items = (const float*)d_in[2]; // (50000,128)
  const float* W = (const float*)d_in[3];     // (256,128)
  const float* bias = (const float*)d_in[4];  // (128,)
  const float* gamma = (const float*)d_in[5]; // (128,)
  const float* beta = (const float*)d_in[6];  // (128,)

  float* ws = (float*)d_ws;
  float* hraw = ws;                                   // 262144 f
  float* hfin = ws + 262144;                          // 262144 f
  float* meanv = ws + 524288;                         // 128 f
  float* rsv = ws + 524416;                           // 128 f
  unsigned* V0u = (unsigned*)(ws + 524544);           // 2048 u32
  float* simv = ws + 526592;                          // 2048 f
  float* norms = ws + 528640;                         // 2 f (Hmax^2, Amax^2)
  unsigned long long* rowslot =
      (unsigned long long*)(ws + 528642);             // 2048 u64 (8B aligned)
  unsigned short* hb = (unsigned short*)(ws + 532740); // 262144 bf16
  unsigned short* ib = (unsigned short*)(ws + 663812); // 12.8MB bf16 (16B aligned)
  float* dout = (float*)d_out;                        // 2050 floats

  hipLaunchKernelGGL(k_hraw, dim3(2048), dim3(128), 0, stream, xfeat, W, bias, hraw, rowslot, V0u, norms);
  hipLaunchKernelGGL(k_bca, dim3(1563), dim3(256), 0, stream, items, ib, norms);
  hipLaunchKernelGGL(k_bnstats, dim3(128), dim3(256), 0, stream, hraw, meanv, rsv);
  hipLaunchKernelGGL(k_apply, dim3(1024), dim3(256), 0, stream, hraw, meanv, rsv, gamma, beta, hfin, hb, norms);
  hipLaunchKernelGGL(k_seed, dim3(256), dim3(256), 0, stream, hb, ib, norms, V0u);
  hipLaunchKernelGGL(k_screen, dim3(2048), dim3(256), 0, stream, hb, hfin, items, ib, V0u, norms, rowslot);
  hipLaunchKernelGGL(k_final, dim3(2048), dim3(64), 0, stream, rowslot, uid, items, dout, simv);
  hipLaunchKernelGGL(k_reduce, dim3(1), dim3(256), 0, stream, simv, dout);
}

// Round 18
// 335.908 us; speedup vs baseline: 1.7305x; 1.0609x over previous
//
#include <hip/hip_runtime.h>
#include <math.h>

#define TINYF 1.17549435e-38f
#define GMAX 16.0f   // hard upper bound on gumbel (15.9424) + slack
#define NT16 3125    // 50000 / 16 exactly
#define SPT16 49     // tiles per span (64 spans x 49 >= 3125)

typedef __attribute__((ext_vector_type(8))) short bf16x8;
typedef __attribute__((ext_vector_type(4))) float f32x4;

// ---------------- threefry2x32, key = (0, 42) ----------------
__device__ __forceinline__ unsigned rotl32(unsigned x, int r) {
  return (x << r) | (x >> (32 - r));
}

__device__ __forceinline__ unsigned tf2x32_xor(unsigned x0, unsigned x1) {
  const unsigned k0 = 0u, k1 = 42u, k2 = 0x1BD11BF0u;  // 0x1BD11BDA ^ 0 ^ 42
  x0 += k0; x1 += k1;
#define TFR(r) { x0 += x1; x1 = rotl32(x1, r); x1 ^= x0; }
  TFR(13) TFR(15) TFR(26) TFR(6)
  x0 += k1; x1 += k2 + 1u;
  TFR(17) TFR(29) TFR(16) TFR(24)
  x0 += k2; x1 += k0 + 2u;
  TFR(13) TFR(15) TFR(26) TFR(6)
  x0 += k0; x1 += k1 + 3u;
  TFR(17) TFR(29) TFR(16) TFR(24)
  x0 += k1; x1 += k2 + 4u;
  TFR(13) TFR(15) TFR(26) TFR(6)
  x0 += k2; x1 += k0 + 5u;
#undef TFR
  return x0 ^ x1;
}

__device__ __forceinline__ float gumbel_from_bits(unsigned bits) {
  float f = __uint_as_float((bits >> 9) | 0x3f800000u) - 1.0f;
  float u = fmaxf(f, TINYF);
  return -logf(-logf(u));
}

// order-preserving float->uint (monotone)
__device__ __forceinline__ unsigned ordf(float v) {
  unsigned b = __float_as_uint(v);
  return (b & 0x80000000u) ? ~b : (b | 0x80000000u);
}
__device__ __forceinline__ float unordf(unsigned u) {
  unsigned b = (u & 0x80000000u) ? (u & 0x7FFFFFFFu) : ~u;
  return __uint_as_float(b);
}

// fp32 -> bf16 RNE (bit trick)
__device__ __forceinline__ unsigned short f2bf(float f) {
  unsigned u = __float_as_uint(f);
  unsigned r = u + 0x7FFFu + ((u >> 16) & 1u);
  return (unsigned short)(r >> 16);
}
__device__ __forceinline__ unsigned pk2(float a, float b) {
  return (unsigned)f2bf(a) | ((unsigned)f2bf(b) << 16);
}
// XOR swizzle within a 16-row x 256B tile (kills stride-256B bank conflicts)
__device__ __forceinline__ int bswz(int b) { return b ^ (((b >> 8) & 7) << 4); }

// ---- candidate resolution. Tier-2 threshold from max(V0u, rowslot) --
// fresh + monotone. Fast u-space pre-test with HW exp (no false reject;
// ~2e-5 over-accept filtered by the exact path). ONE noinline copy.
__device__ __attribute__((noinline)) void resolve_cand(
    int R, int J, float s, float ERRC,
    const float* __restrict__ hfin, const float* __restrict__ items,
    const unsigned* __restrict__ V0u,
    unsigned long long* __restrict__ rowslot, const volatile unsigned* hiw) {
  const unsigned v0 = V0u[R];
  const unsigned hi0 = hiw[2 * R + 1];
  float tv = v0 ? unordf(v0) : -3.4e38f;
  if (hi0) tv = fmaxf(tv, unordf(hi0));
  const float thr2 = tv - ERRC;  // sound: s_fp32 + g <= s_bf16 + ERRC + g
  const float d = thr2 - s;
  const unsigned bits = tf2x32_xor(0u, (unsigned)R * 50000u + (unsigned)J);
  const float f = __uint_as_float((bits >> 9) | 0x3f800000u) - 1.0f;
  const float u = fmaxf(f, TINYF);
  const float thr_u = __expf(-__expf(-d)) * (1.0f - 2e-5f);
  if (u < thr_u) return;             // sound fast reject
  const float g = -logf(-logf(u));   // exact gumbel (rare path)
  if (s + g < thr2) return;          // exact tier-2
  const float4* hp = (const float4*)(hfin + (size_t)R * 128);
  const float4* ap = (const float4*)(items + (size_t)J * 128);
  float4 a4 = {0.f, 0.f, 0.f, 0.f};
#pragma unroll
  for (int k = 0; k < 32; ++k) {
    float4 h = hp[k];
    float4 b = ap[k];
    a4.x = fmaf(h.x, b.x, a4.x);
    a4.y = fmaf(h.y, b.y, a4.y);
    a4.z = fmaf(h.z, b.z, a4.z);
    a4.w = fmaf(h.w, b.w, a4.w);
  }
  const float v = ((a4.x + a4.y) + (a4.z + a4.w)) + g;
  const unsigned ov = ordf(v);
  if (ov >= hiw[2 * R + 1]) {  // '>=': let atomicMax resolve smaller-J ties
    const unsigned long long pk =
        ((unsigned long long)ov << 32) | (0xFFFFFFFFu - (unsigned)J);
    atomicMax(&rowslot[R], pk);
  }
}

// ---- fused: h = x@W+b (blocks 0..1023, 2 rows each) AND items->bf16 +
// max item row-norm^2 (blocks 1024..2586). Independent work, one launch;
// overlaps the W-bound GEMM with the HBM-bound convert. Workspace init
// (rowslot/V0u/norms) moved to hipMemsetAsync before this launch.
__global__ void k_pre(const float* __restrict__ x, const float* __restrict__ W,
                      const float* __restrict__ b, float* __restrict__ hraw,
                      const float* __restrict__ items,
                      unsigned short* __restrict__ ib, float* __restrict__ norms) {
  __shared__ float sx[2][256];
  __shared__ float red[4];
  const int t = threadIdx.x;
  const int bid = blockIdx.x;
  if (bid < 1024) {
    const int rr = t >> 7, d = t & 127;
    const int i = bid * 2 + rr;
    sx[rr][d] = x[i * 256 + d];
    sx[rr][d + 128] = x[i * 256 + 128 + d];
    __syncthreads();
    double acc = 0.0;
    for (int k = 0; k < 256; ++k)
      acc = fma((double)sx[rr][k], (double)W[k * 128 + d], acc);
    hraw[i * 128 + d] = (float)acc + b[d];
  } else {
    const int bb = bid - 1024;  // 0..1562
    const int row = bb * 32 + (t >> 3);
    const int rc = row > 49999 ? 49999 : row;  // dup row: harmless for max
    const int c = (t & 7) * 16;
    const float4* p = (const float4*)(items + (size_t)rc * 128 + c);
    const float4 v0 = p[0], v1 = p[1], v2 = p[2], v3 = p[3];
    float ss = v0.x * v0.x + v0.y * v0.y + v0.z * v0.z + v0.w * v0.w +
               v1.x * v1.x + v1.y * v1.y + v1.z * v1.z + v1.w * v1.w +
               v2.x * v2.x + v2.y * v2.y + v2.z * v2.z + v2.w * v2.w +
               v3.x * v3.x + v3.y * v3.y + v3.z * v3.z + v3.w * v3.w;
    if (row <= 49999) {
      uint4 o0, o1;
      o0.x = pk2(v0.x, v0.y); o0.y = pk2(v0.z, v0.w);
      o0.z = pk2(v1.x, v1.y); o0.w = pk2(v1.z, v1.w);
      o1.x = pk2(v2.x, v2.y); o1.y = pk2(v2.z, v2.w);
      o1.z = pk2(v3.x, v3.y); o1.w = pk2(v3.z, v3.w);
      uint4* dst = (uint4*)(ib + (size_t)row * 128 + c);
      dst[0] = o0; dst[1] = o1;
    }
    ss += __shfl_xor(ss, 1);  // sum 8-lane row group
    ss += __shfl_xor(ss, 2);
    ss += __shfl_xor(ss, 4);
    ss = fmaxf(ss, __shfl_xor(ss, 8));   // max across rows in wave
    ss = fmaxf(ss, __shfl_xor(ss, 16));
    ss = fmaxf(ss, __shfl_xor(ss, 32));
    if ((t & 63) == 0) red[t >> 6] = ss;
    __syncthreads();
    if (t == 0) {
      float mx = fmaxf(fmaxf(red[0], red[1]), fmaxf(red[2], red[3]));
      atomicMax((unsigned*)&norms[1], __float_as_uint(mx));
    }
  }
}

// ---------------- BN stats per column (f64) ----------------
__global__ void k_bnstats(const float* __restrict__ hraw,
                          float* __restrict__ meanv, float* __restrict__ rsv) {
  __shared__ double red[256];
  const int d = blockIdx.x;   // 128 blocks
  const int t = threadIdx.x;  // 256 threads
  double s = 0.0;
  for (int i = t; i < 2048; i += 256) s += (double)hraw[i * 128 + d];
  red[t] = s;
  __syncthreads();
  for (int off = 128; off > 0; off >>= 1) {
    if (t < off) red[t] += red[t + off];
    __syncthreads();
  }
  const float m = (float)(red[0] * (1.0 / 2048.0));
  __syncthreads();
  double v = 0.0;
  for (int i = t; i < 2048; i += 256) {
    float dd = __fsub_rn(hraw[i * 128 + d], m);
    v += (double)dd * (double)dd;
  }
  red[t] = v;
  __syncthreads();
  for (int off = 128; off > 0; off >>= 1) {
    if (t < off) red[t] += red[t + off];
    __syncthreads();
  }
  if (t == 0) {
    float var = (float)(red[0] * (1.0 / 2048.0));
    float vpe = __fadd_rn(var, 1e-5f);
    meanv[d] = m;
    rsv[d] = (float)(1.0 / sqrt((double)vpe));
  }
}

// ---------------- apply BN + leaky relu, emit bf16 copy + max row-norm ------
__global__ void k_apply(const float* __restrict__ hraw,
                        const float* __restrict__ meanv, const float* __restrict__ rsv,
                        const float* __restrict__ gamma, const float* __restrict__ beta,
                        float* __restrict__ hfin, unsigned short* __restrict__ hb,
                        float* __restrict__ norms) {
  __shared__ float red[256];
  const int t = threadIdx.x;
  const int idx = blockIdx.x * 256 + t;  // 2 rows per block
  const int d = idx & 127;
  float h = hraw[idx];
  float hn = __fadd_rn(__fmul_rn(__fmul_rn(__fsub_rn(h, meanv[d]), rsv[d]), gamma[d]), beta[d]);
  float o = (hn >= 0.0f) ? hn : __fmul_rn(0.01f, hn);
  hfin[idx] = o;
  hb[idx] = f2bf(o);
  red[t] = o * o;
  __syncthreads();
  for (int off = 64; off > 0; off >>= 1) {
    if ((t & 127) < off) red[t] += red[t + off];
    __syncthreads();
  }
  if ((t & 127) == 0) atomicMax((unsigned*)&norms[0], __float_as_uint(red[t]));
}

// ---------------- V0 seed via MFMA: lower bound on max_{j<1024}(s+g) -------
// grid 256 = rg*8 + jspan. Same fragment layout as k_screen; B-frags direct
// from ib (L2-hot). atomicMax(V0u[R], ordf(max(s_bf16+g) - ERRC)) -- sound
// lower bound since s_fp32 >= s_bf16 - ERRC pointwise.
__global__ __launch_bounds__(256, 2) void k_seed(
    const unsigned short* __restrict__ hb, const unsigned short* __restrict__ ib,
    const float* __restrict__ norms, unsigned* __restrict__ V0u) {
  const int t = threadIdx.x;
  const int w = t >> 6, l = t & 63;
  const int lg = l >> 4, lr = l & 15;
  const int rg = blockIdx.x >> 3;     // 0..31
  const int jspan = blockIdx.x & 7;   // 0..7
  const int r0w = rg * 64 + w * 16;
  const float ERRC = 0.004f * sqrtf(norms[0] * norms[1]) + 0.01f;

  const unsigned short* aB0 = hb + (size_t)(r0w + lr) * 128 + lg * 8;
  bf16x8 Afrag[4];
#pragma unroll
  for (int kb = 0; kb < 4; ++kb) Afrag[kb] = *(const bf16x8*)(aB0 + kb * 32);

  float vmax[4] = {-3.4e38f, -3.4e38f, -3.4e38f, -3.4e38f};
  for (int itr = 0; itr < 8; ++itr) {
    const int J = jspan * 128 + itr * 16 + lr;
    const unsigned short* bp = ib + (size_t)J * 128 + lg * 8;
    f32x4 acc = (f32x4){0.f, 0.f, 0.f, 0.f};
#pragma unroll
    for (int kb = 0; kb < 4; ++kb)
      acc = __builtin_amdgcn_mfma_f32_16x16x32_bf16(Afrag[kb], *(const bf16x8*)(bp + kb * 32), acc, 0, 0, 0);
#pragma unroll
    for (int q = 0; q < 4; ++q) {
      const int R = r0w + lg * 4 + q;
      const float g = gumbel_from_bits(tf2x32_xor(0u, (unsigned)R * 50000u + (unsigned)J));
      vmax[q] = fmaxf(vmax[q], acc[q] + g);
    }
  }
#pragma unroll
  for (int m = 1; m <= 8; m <<= 1)
#pragma unroll
    for (int q = 0; q < 4; ++q) vmax[q] = fmaxf(vmax[q], __shfl_xor(vmax[q], m));
  if (lr == 0) {
#pragma unroll
    for (int q = 0; q < 4; ++q)
      atomicMax(&V0u[r0w + lg * 4 + q], ordf(vmax[q] - ERRC));
  }
}

// ---------------- bf16 MFMA screen: zero-barrier, 32 rows/wave -------------
// Round 17 zero-barrier pipeline with the row-tile DOUBLED per wave: 32 rows
// (Afrag[2][4]), grid 1024 = 16 rg x 64 spans. Halves wave-iters AND the
// DMA j-redundancy (16 row-groups re-stage each span, was 32); the fixed
// per-iter costs (4 DMA issues, counted vmcnt, thresholds, loop) amortize
// over 2x the MFMA/push work. Everything else identical to round 17.
__global__ __launch_bounds__(256, 2) void k_screen(
    const unsigned short* __restrict__ hb, const float* __restrict__ hfin,
    const float* __restrict__ items, const unsigned short* __restrict__ ib,
    const unsigned* __restrict__ V0u,
    const float* __restrict__ norms, unsigned long long* __restrict__ rowslot) {
  __shared__ __align__(16) unsigned short Bs[4][2][16 * 128];  // 32KB
  __shared__ unsigned qk[4][128];  // per-wave candidate queues
  __shared__ float qsh[4][128];

  const int t = threadIdx.x;
  const int w = t >> 6, l = t & 63;
  const int lg = l >> 4, lr = l & 15;
  const int rg = blockIdx.x >> 6;       // 0..15
  const int span = blockIdx.x & 63;
  const int r0w = rg * 128 + w * 32;    // this wave's 32 rows
  const int tile0 = span * SPT16;
  int nt = NT16 - tile0;
  nt = nt < 0 ? 0 : (nt > SPT16 ? SPT16 : nt);
  if (nt == 0) return;  // block-uniform (span 63 has 38)

  const float ERRC = 0.004f * sqrtf(norms[0] * norms[1]) + 0.01f;
  const volatile unsigned* hiw = (const volatile unsigned*)rowslot;  // hi @ 2R+1

  // resident A fragments: lane holds rows (r0w + lr) and (+16), 8 k each
  const unsigned short* aB0 = hb + (size_t)(r0w + lr) * 128 + lg * 8;
  bf16x8 Afrag[2][4];
#pragma unroll
  for (int kb = 0; kb < 4; ++kb) {
    Afrag[0][kb] = *(const bf16x8*)(aB0 + kb * 32);
    Afrag[1][kb] = *(const bf16x8*)(aB0 + 16 * 128 + kb * 32);
  }

  // wave-private staging: chunk c covers LDS bytes [c*1024, +1024);
  // lane l -> LDS off c*1024 + l*16; tile-local row = c*4 + (l>>4),
  // col = (l&15)*16; swizzled global col = col ^ ((row&7)<<4).
  char* wlds = (char*)Bs + w * 8192;
  const char* ibc = (const char*)ib;
  int so[4];
#pragma unroll
  for (int c = 0; c < 4; ++c) {
    const int row = c * 4 + (l >> 4);
    const int col = (l & 15) * 16;
    so[c] = row * 256 + (col ^ ((row & 7) << 4));
  }

#define ISSUE(tl, pbuf)                                                        \
  {                                                                            \
    const char* gs = ibc + (size_t)(tl) * 4096;                                \
    char* ld = wlds + (pbuf) * 4096;                                           \
    __builtin_amdgcn_global_load_lds((const unsigned*)(gs + so[0]),            \
                                     (unsigned*)(ld), 16, 0, 0);               \
    __builtin_amdgcn_global_load_lds((const unsigned*)(gs + so[1]),            \
                                     (unsigned*)(ld + 1024), 16, 0, 0);        \
    __builtin_amdgcn_global_load_lds((const unsigned*)(gs + so[2]),            \
                                     (unsigned*)(ld + 2048), 16, 0, 0);        \
    __builtin_amdgcn_global_load_lds((const unsigned*)(gs + so[3]),            \
                                     (unsigned*)(ld + 3072), 16, 0, 0);        \
  }
#define WAITVM4() { asm volatile("s_waitcnt vmcnt(4)" ::: "memory"); \
                    __builtin_amdgcn_sched_barrier(0); }
#define WAITVM0() { asm volatile("s_waitcnt vmcnt(0)" ::: "memory"); \
                    __builtin_amdgcn_sched_barrier(0); }

  // prologue: stage tile0 -> buf 0
  ISSUE(tile0, 0)

  const unsigned long long lml = (1ull << l) - 1ull;  // lanes below me
  unsigned qn = 0;     // wave-uniform queue count (SGPR)
  float th1[2][4];     // tier-1 thresholds (registers)

  int pb = 0;
  for (int it = 0; it < nt; ++it) {
    const int j0 = (tile0 + it) * 16;

    // ---- issue next tile; counted wait retires ONLY the current tile ----
    if (it + 1 < nt) {
      ISSUE(tile0 + it + 1, pb ^ 1)
      WAITVM4()
    } else {
      WAITVM0()
    }

    // ---- refresh tier-1 thresholds every 8 tiles (stale-low is safe) ----
    if ((it & 7) == 0) {
      float tvl = -3.4e38f;
      if (l < 32) {
        const int R = r0w + l;
        const unsigned v0 = V0u[R];
        if (v0) tvl = unordf(v0);
        const unsigned hi = hiw[2 * R + 1];
        if (hi) tvl = fmaxf(tvl, unordf(hi));
      }
#pragma unroll
      for (int rt = 0; rt < 2; ++rt)
#pragma unroll
        for (int q = 0; q < 4; ++q)
          th1[rt][q] = __shfl(tvl, rt * 16 + lg * 4 + q) - GMAX - ERRC;
    }

    // ---- 4 ds_read + 8 MFMA (two chains per row-tile) from buf pb ----
    f32x4 p0 = (f32x4){0.f, 0.f, 0.f, 0.f};
    f32x4 p1 = (f32x4){0.f, 0.f, 0.f, 0.f};
    f32x4 q0 = (f32x4){0.f, 0.f, 0.f, 0.f};
    f32x4 q1 = (f32x4){0.f, 0.f, 0.f, 0.f};
    const char* tb = wlds + pb * 4096;
    {
      bf16x8 b0 = *(const bf16x8*)(tb + bswz(lr * 256 + 0 * 64 + lg * 16));
      bf16x8 b1 = *(const bf16x8*)(tb + bswz(lr * 256 + 1 * 64 + lg * 16));
      bf16x8 b2 = *(const bf16x8*)(tb + bswz(lr * 256 + 2 * 64 + lg * 16));
      bf16x8 b3 = *(const bf16x8*)(tb + bswz(lr * 256 + 3 * 64 + lg * 16));
      p0 = __builtin_amdgcn_mfma_f32_16x16x32_bf16(Afrag[0][0], b0, p0, 0, 0, 0);
      q0 = __builtin_amdgcn_mfma_f32_16x16x32_bf16(Afrag[1][0], b0, q0, 0, 0, 0);
      p1 = __builtin_amdgcn_mfma_f32_16x16x32_bf16(Afrag[0][1], b1, p1, 0, 0, 0);
      q1 = __builtin_amdgcn_mfma_f32_16x16x32_bf16(Afrag[1][1], b1, q1, 0, 0, 0);
      p0 = __builtin_amdgcn_mfma_f32_16x16x32_bf16(Afrag[0][2], b2, p0, 0, 0, 0);
      q0 = __builtin_amdgcn_mfma_f32_16x16x32_bf16(Afrag[1][2], b2, q0, 0, 0, 0);
      p1 = __builtin_amdgcn_mfma_f32_16x16x32_bf16(Afrag[0][3], b3, p1, 0, 0, 0);
      q1 = __builtin_amdgcn_mfma_f32_16x16x32_bf16(Afrag[1][3], b3, q1, 0, 0, 0);
    }
    const f32x4 acc0 = p0 + p1;
    const f32x4 acc1 = q0 + q1;

    // ---- tier-1 push via ballot compaction; per-wave drain at >=64 ----
    // C/D layout: col = lane&15 (lr) -> J = j0+lr; row = rt*16+(lane>>4)*4+q.
#pragma unroll
    for (int rt = 0; rt < 2; ++rt)
#pragma unroll
      for (int q = 0; q < 4; ++q) {
        const float s = rt ? acc1[q] : acc0[q];
        const int J = j0 + lr;
        const bool c = (s >= th1[rt][q]);
        const unsigned long long m = __ballot(c);
        if (m) {
          if (c) {
            const unsigned idx = qn + (unsigned)__popcll(m & lml);
            qk[w][idx] = ((unsigned)(rt * 16 + lg * 4 + q) << 16) | (unsigned)J;
            qsh[w][idx] = s;
          }
          qn += (unsigned)__popcll(m);
          if (qn >= 64) {  // drain fully (qn <= 127 -> fits cap 128)
            for (unsigned i = (unsigned)l; i < qn; i += 64) {
              const unsigned key = qk[w][i];
              resolve_cand(r0w + (int)(key >> 16), (int)(key & 0xFFFFu),
                           qsh[w][i], ERRC, hfin, items, V0u, rowslot, hiw);
            }
            qn = 0;
          }
        }
      }

    pb ^= 1;
  }

  // ---- final drain ----
  for (unsigned i = (unsigned)l; i < qn; i += 64) {
    const unsigned key = qk[w][i];
    resolve_cand(r0w + (int)(key >> 16), (int)(key & 0xFFFFu),
                 qsh[w][i], ERRC, hfin, items, V0u, rowslot, hiw);
  }
#undef ISSUE
#undef WAITVM4
#undef WAITVM0
}

// ---------------- final: read row winner + cosine sim (one wave/row) -------
__global__ void k_final(const unsigned long long* __restrict__ rowslot,
                        const int* __restrict__ uid, const float* __restrict__ items,
                        float* __restrict__ dout, float* __restrict__ simv) {
  const int r = blockIdx.x;
  const int lane = threadIdx.x;  // 64
  const unsigned long long pk = rowslot[r];  // nonzero: winner always resolves
  const int bi = (int)(0xFFFFFFFFu - (unsigned)pk);
  if (lane == 0) dout[r] = (float)bi;

  const int orig = uid[r * 2 + 1];
  float o1 = items[(size_t)orig * 128 + lane];
  float o2 = items[(size_t)orig * 128 + 64 + lane];
  float p1 = items[(size_t)bi * 128 + lane];
  float p2 = items[(size_t)bi * 128 + 64 + lane];
  float d = o1 * p1 + o2 * p2;
  float s1 = o1 * o1 + o2 * o2;
  float s2 = p1 * p1 + p2 * p2;
  for (int off = 32; off > 0; off >>= 1) {
    d += __shfl_down(d, off);
    s1 += __shfl_down(s1, off);
    s2 += __shfl_down(s2, off);
  }
  if (lane == 0) {
    float n1 = fmaxf(sqrtf(s1), 1e-6f);
    float n2 = fmaxf(sqrtf(s2), 1e-6f);
    float sim = d / (n1 * n2);
    simv[r] = (sim + 1.0f) * 0.5f;
  }
}

// ---------------- final scalar reductions ----------------
__global__ void k_reduce(const float* __restrict__ simv, float* __restrict__ dout) {
  __shared__ double rl[256];
  __shared__ double rs[256];
  const int t = threadIdx.x;
  double L = 0.0, S = 0.0;
  for (int i = t; i < 2048; i += 256) {
    double s = (double)simv[i];
    double dd = s - 0.5;
    L += dd * dd;
    S += s;
  }
  rl[t] = L; rs[t] = S;
  __syncthreads();
  for (int off = 128; off > 0; off >>= 1) {
    if (t < off) { rl[t] += rl[t + off]; rs[t] += rs[t + off]; }
    __syncthreads();
  }
  if (t == 0) {
    dout[2048] = (float)(rl[0] * (1.0 / 2048.0));
    dout[2049] = (float)(rs[0] * (1.0 / 2048.0));
  }
}

extern "C" void kernel_launch(void* const* d_in, const int* in_sizes, int n_in,
                              void* d_out, int out_size, void* d_ws, size_t ws_size,
                              hipStream_t stream) {
  const int* uid = (const int*)d_in[0];       // (2048,2) int32
  const float* xfeat = (const float*)d_in[1]; // (2048,256)
  const float* items = (const float*)d_in[2]; // (50000,128)
  const float* W = (const float*)d_in[3];     // (256,128)
  const float* bias = (const float*)d_in[4];  // (128,)
  const float* gamma = (const float*)d_in[5]; // (128,)
  const float* beta = (const float*)d_in[6];  // (128,)

  float* ws = (float*)d_ws;
  float* hraw = ws;                                   // 262144 f
  float* hfin = ws + 262144;                          // 262144 f
  float* meanv = ws + 524288;                         // 128 f
  float* rsv = ws + 524416;                           // 128 f
  unsigned* V0u = (unsigned*)(ws + 524544);           // 2048 u32
  float* simv = ws + 526592;                          // 2048 f
  float* norms = ws + 528640;                         // 2 f (Hmax^2, Amax^2)
  unsigned long long* rowslot =
      (unsigned long long*)(ws + 528642);             // 2048 u64 (8B aligned)
  unsigned short* hb = (unsigned short*)(ws + 532740); // 262144 bf16
  unsigned short* ib = (unsigned short*)(ws + 663812); // 12.8MB bf16 (16B aligned)
  float* dout = (float*)d_out;                        // 2050 floats

  // zero V0u and norms+rowslot (contiguous) before any atomics
  hipMemsetAsync(V0u, 0, 2048 * 4, stream);
  hipMemsetAsync(norms, 0, 8 + 2048 * 8, stream);

  hipLaunchKernelGGL(k_pre, dim3(2587), dim3(256), 0, stream, xfeat, W, bias, hraw, items, ib, norms);
  hipLaunchKernelGGL(k_bnstats, dim3(128), dim3(256), 0, stream, hraw, meanv, rsv);
  hipLaunchKernelGGL(k_apply, dim3(1024), dim3(256), 0, stream, hraw, meanv, rsv, gamma, beta, hfin, hb, norms);
  hipLaunchKernelGGL(k_seed, dim3(256), dim3(256), 0, stream, hb, ib, norms, V0u);
  hipLaunchKernelGGL(k_screen, dim3(1024), dim3(256), 0, stream, hb, hfin, items, ib, V0u, norms, rowslot);
  hipLaunchKernelGGL(k_final, dim3(2048), dim3(64), 0, stream, rowslot, uid, items, dout, simv);
  hipLaunchKernelGGL(k_reduce, dim3(1), dim3(256), 0, stream, simv, dout);
}